// Round 16
// baseline (40.394 us; speedup 1.0000x reference)
//
#include <hip/hip_runtime.h>
#include <math.h>

#define NN 1024
#define K 16

typedef _Float16 f16;
typedef f16 f16x8 __attribute__((ext_vector_type(8)));
typedef float f32x4 __attribute__((ext_vector_type(4)));

typedef __attribute__((address_space(1))) void gvoid;
typedef __attribute__((address_space(3))) void svoid;

// fragment region byte offsets (within f16 frag buffer; same layout in d_ws and LDS)
#define W0F_OFF 0          // 8 frags  (kt2 x nt4)
#define W1F_OFF 8192       // 32 frags (q4 x kt2 x nt4)
#define W2F_OFF 40960      // 32 frags (q4 x kt2 x nt4)
#define WLF_OFF 73728      // 2 frags  (kt2)
#define B1F_OFF 75776      // 2 frags  (kt2)
#define FRAG_BYTES 77824   // 76 frags x 1KB  (= 4864 x 16B)

#define MFMA16(a,b,c) __builtin_amdgcn_mfma_f32_16x16x32_f16((a),(b),(c),0,0,0)

// ---- DPP cross-lane helpers (VALU pipe, not DS) ----
template<int CTRL>
__device__ __forceinline__ float dppf(float v) {
    return __int_as_float(__builtin_amdgcn_update_dpp(0, __float_as_int(v), CTRL, 0xF, 0xF, true));
}
template<int CTRL>
__device__ __forceinline__ int dppi(int v) {
    return __builtin_amdgcn_update_dpp(0, v, CTRL, 0xF, 0xF, true);
}
// sum over each aligned group of 16 lanes; result replicated in all 16
__device__ __forceinline__ float rowsum16(float v) {
    v += dppf<0xB1>(v);    // quad_perm [1,0,3,2]  (xor1)
    v += dppf<0x4E>(v);    // quad_perm [2,3,0,1]  (xor2)
    v += dppf<0x124>(v);   // row_ror:4
    v += dppf<0x128>(v);   // row_ror:8
    return v;
}
__device__ __forceinline__ void argmin_step(float& bv, int& bidx, float ov, int oi) {
    bool t = (ov < bv) || (ov == bv && oi < bidx);
    bv = t ? ov : bv;
    bidx = t ? oi : bidx;
}

// -------------------- fused: topk (blocks 0..1023) + weight prep (1024..1042) --------------------
__global__ __launch_bounds__(256) void pre_kernel(const float* __restrict__ D,
                                                  const float* __restrict__ W0,
                                                  const float* __restrict__ W1,
                                                  const float* __restrict__ W2,
                                                  const float* __restrict__ Wl,
                                                  const float* __restrict__ b1,
                                                  int* __restrict__ selfIdx,
                                                  int* __restrict__ nbrIdx,
                                                  f16* __restrict__ frag) {
    if (blockIdx.x >= 1024) {
        int c = (blockIdx.x - 1024) * 256 + threadIdx.x;   // 0..4863
        if (c >= 76 * 64) return;
        int fg   = c >> 6;
        int lane = c & 63;
        int lrow = lane & 15;
        int kgrp = lane >> 4;
        float src[8];
        if (fg < 8) {
            int kt = fg >> 2, nt = fg & 3;
            int n = nt * 16 + lrow;
#pragma unroll
            for (int i = 0; i < 8; ++i) src[i] = W0[(kt * 32 + kgrp * 8 + i) * 64 + n];
        } else if (fg < 40) {
            int t = fg - 8;
            int q = t >> 3, kt = (t >> 2) & 1, nt = t & 3;
            int f = nt * 16 + lrow;
#pragma unroll
            for (int i = 0; i < 8; ++i) src[i] = W1[f * 256 + q * 64 + kt * 32 + kgrp * 8 + i];
        } else if (fg < 72) {
            int t = fg - 40;
            int q = t >> 3, kt = (t >> 2) & 1, nt = t & 3;
            int o = nt * 16 + lrow;
#pragma unroll
            for (int i = 0; i < 8; ++i) src[i] = W2[(kt * 32 + kgrp * 8 + i) * 256 + q * 64 + o];
        } else if (fg < 74) {
            int kt = fg - 72;
#pragma unroll
            for (int i = 0; i < 8; ++i) src[i] = Wl[(kt * 32 + kgrp * 8 + i) * 16 + lrow];
        } else {
            int kt = fg - 74;
#pragma unroll
            for (int i = 0; i < 8; ++i) src[i] = b1[lrow * 64 + kt * 32 + kgrp * 8 + i];
        }
        f16x8 v;
#pragma unroll
        for (int i = 0; i < 8; ++i) v[i] = (f16)src[i];
        *(f16x8*)((unsigned char*)frag + fg * 1024 + lane * 16) = v;
        return;
    }

    // ---- top-17 smallest per row; lane owns contiguous 16 elements ----
    int row  = blockIdx.x * 4 + (threadIdx.x >> 6);
    int lane = threadIdx.x & 63;
    const float* Drow = D + (size_t)row * NN + lane * 16;

    float v[16];
    {
        float4 t0 = *(const float4*)(Drow);
        float4 t1 = *(const float4*)(Drow + 4);
        float4 t2 = *(const float4*)(Drow + 8);
        float4 t3 = *(const float4*)(Drow + 12);
        v[0]=t0.x;  v[1]=t0.y;  v[2]=t0.z;  v[3]=t0.w;
        v[4]=t1.x;  v[5]=t1.y;  v[6]=t1.z;  v[7]=t1.w;
        v[8]=t2.x;  v[9]=t2.y;  v[10]=t2.z; v[11]=t2.w;
        v[12]=t3.x; v[13]=t3.y; v[14]=t3.z; v[15]=t3.w;
    }

    for (int t = 0; t < K + 1; ++t) {
        float bv = v[0]; int bj = 0;
#pragma unroll
        for (int j = 1; j < 16; ++j)
            if (v[j] < bv) { bv = v[j]; bj = j; }
        int bidx = lane * 16 + bj;     // global index; strict < keeps lowest j
        // wave argmin: 4 DPP steps (within 16 lanes) + 2 shfl (16, 32)
        argmin_step(bv, bidx, dppf<0xB1>(bv),  dppi<0xB1>(bidx));
        argmin_step(bv, bidx, dppf<0x4E>(bv),  dppi<0x4E>(bidx));
        argmin_step(bv, bidx, dppf<0x124>(bv), dppi<0x124>(bidx));
        argmin_step(bv, bidx, dppf<0x128>(bv), dppi<0x128>(bidx));
        argmin_step(bv, bidx, __shfl_xor(bv, 16), __shfl_xor(bidx, 16));
        argmin_step(bv, bidx, __shfl_xor(bv, 32), __shfl_xor(bidx, 32));

        if (lane == 0) {
            if (t == 0) selfIdx[row] = bidx;
            else        nbrIdx[row * K + (t - 1)] = bidx;
        }
        // invalidate winner — compile-time indices only
        int hit = ((bidx >> 4) == lane) ? (bidx & 15) : 16;
#pragma unroll
        for (int j = 0; j < 16; ++j) v[j] = (j == hit) ? INFINITY : v[j];
    }
}

// -------------------- main: 8 waves x 2 nodes each; 1 block per CU --------------------
// Two independent per-node streams per wave -> instruction-level latency hiding;
// B-fragment ds_reads shared between the two streams (half the weight reads/node).
__global__ __launch_bounds__(512, 2) void node_kernel(
    const float* __restrict__ h,
    const float* __restrict__ b0, const float* __restrict__ b2,
    const float* __restrict__ bl,
    const f16* __restrict__ frag,
    const int* __restrict__ selfIdx, const int* __restrict__ nbrIdx,
    float* __restrict__ out) {

    __shared__ __attribute__((aligned(16))) unsigned char sfrag[FRAG_BYTES];
    __shared__ __attribute__((aligned(16))) f16 sbuf[16 * 1152];   // 16 node-bufs [16][72]
    __shared__ __attribute__((aligned(16))) float sxr[16 * 256];   // 16 node xr bufs

    const int tid  = threadIdx.x;
    const int wid  = tid >> 6;          // 0..7
    const int lane = tid & 63;
    const int lrow = lane & 15;
    const int kgrp = lane >> 4;
    const int n0   = blockIdx.x * 16 + wid * 2;

    // ---------- 1. async frag staging: global -> LDS ----------
    {
        const unsigned char* gbase = (const unsigned char*)frag;
#pragma unroll
        for (int it = 0; it < 10; ++it) {
            int chunk = it * 512 + wid * 64;           // 16B-unit index (wave-uniform)
            if (chunk < 4864) {
                __builtin_amdgcn_global_load_lds(
                    (gvoid*)(gbase + (size_t)(chunk + lane) * 16),
                    (svoid*)(sfrag + (size_t)chunk * 16),
                    16, 0, 0);
            }
        }
    }

    // ---------- 2. idx + x1/x2 load, A-frags, d (overlaps staging drain) ----------
    const float* hb = h + ((size_t)(n0 >> 10) << 16);   // both nodes in same batch (16 | 1024)

    f16x8 x1f[2][2], lrf[2][2];
    float dv[2];
#pragma unroll
    for (int mt = 0; mt < 2; ++mt) {
        const int node = n0 + mt;
        const int self = selfIdx[node];
        const int nb   = nbrIdx[node * 16 + lrow];
        float dp = 0.f;
#pragma unroll
        for (int kt = 0; kt < 2; ++kt) {
            const float* p1 = hb + nb * 64 + kt * 32 + kgrp * 8;
            const float* p2 = hb + self * 64 + kt * 32 + kgrp * 8;
            float4 a0 = *(const float4*)(p1);
            float4 a1 = *(const float4*)(p1 + 4);
            float4 s0 = *(const float4*)(p2);
            float4 s1 = *(const float4*)(p2 + 4);
            float xs[8] = {a0.x,a0.y,a0.z,a0.w,a1.x,a1.y,a1.z,a1.w};
            float ss[8] = {s0.x,s0.y,s0.z,s0.w,s1.x,s1.y,s1.z,s1.w};
#pragma unroll
            for (int i = 0; i < 8; ++i) {
                float t = xs[i] - ss[i];
                x1f[mt][kt][i] = (f16)xs[i];
                lrf[mt][kt][i] = (f16)t;
                dp = fmaf(t, t, dp);
            }
        }
        dp += __shfl_xor(dp, 16);
        dp += __shfl_xor(dp, 32);
        dv[mt] = dp;
    }

    // ---------- 3. barrier: drains async LDS loads + syncs ----------
    __syncthreads();

    const unsigned char* fb = sfrag;
    f16* buf0 = sbuf + (wid * 2 + 0) * 1152;
    f16* buf1 = sbuf + (wid * 2 + 1) * 1152;
    float* xrb0 = sxr + (wid * 2 + 0) * 256;
    float* xrb1 = sxr + (wid * 2 + 1) * 256;

    // ---------- phase 1: lab = leakyReLU(lr @ W0 + b0) ----------
    f32x4 labf[2][4];
#pragma unroll
    for (int nt = 0; nt < 4; ++nt) {
        float bb = b0[nt * 16 + lrow];
        labf[0][nt] = (f32x4){bb, bb, bb, bb};
        labf[1][nt] = labf[0][nt];
    }
#pragma unroll
    for (int kt = 0; kt < 2; ++kt)
#pragma unroll
        for (int nt = 0; nt < 4; ++nt) {
            f16x8 bf = *(const f16x8*)(fb + W0F_OFF + (kt * 4 + nt) * 1024 + lane * 16);
            labf[0][nt] = MFMA16(lrf[0][kt], bf, labf[0][nt]);
            labf[1][nt] = MFMA16(lrf[1][kt], bf, labf[1][nt]);
        }
#pragma unroll
    for (int nt = 0; nt < 4; ++nt)
#pragma unroll
        for (int j = 0; j < 4; ++j) {
            float v0 = labf[0][nt][j];
            float v1 = labf[1][nt][j];
            v0 = v0 > 0.f ? v0 : 0.02f * v0;
            v1 = v1 > 0.f ? v1 : 0.02f * v1;
            labf[0][nt][j] = v0;
            labf[1][nt][j] = v1;
            buf0[(kgrp*4 + j) * 72 + nt*16 + lrow] = (f16)v0;
            buf1[(kgrp*4 + j) * 72 + nt*16 + lrow] = (f16)v1;
        }

    // ---------- thl = lab@Wl + bl ; b1x = x1 @ b1^T ----------
    f32x4 thlf[2], b1xf[2];
    {
        float blv = bl[lrow];
        thlf[0] = (f32x4){blv, blv, blv, blv};
        thlf[1] = thlf[0];
        b1xf[0] = (f32x4){0.f, 0.f, 0.f, 0.f};
        b1xf[1] = b1xf[0];
#pragma unroll
        for (int kt = 0; kt < 2; ++kt) {
            f16x8 wl = *(const f16x8*)(fb + WLF_OFF + kt * 1024 + lane * 16);
            f16x8 bb = *(const f16x8*)(fb + B1F_OFF + kt * 1024 + lane * 16);
            f16x8 la0 = *(const f16x8*)&buf0[lrow * 72 + kt*32 + kgrp*8];
            f16x8 la1 = *(const f16x8*)&buf1[lrow * 72 + kt*32 + kgrp*8];
            thlf[0] = MFMA16(la0, wl, thlf[0]);
            thlf[1] = MFMA16(la1, wl, thlf[1]);
            b1xf[0] = MFMA16(x1f[0][kt], bb, b1xf[0]);
            b1xf[1] = MFMA16(x1f[1][kt], bb, b1xf[1]);
        }
    }

    // ---------- q-loop (fully unrolled) ----------
    const int pown = lrow >> 2;     // this lane's column's p   (col = lrow = p*4+q')
    f32x4 xof[2][4];
#pragma unroll
    for (int nt = 0; nt < 4; ++nt) {
        xof[0][nt] = (f32x4){0.f, 0.f, 0.f, 0.f};
        xof[1][nt] = xof[0][nt];
    }

#pragma unroll
    for (int q = 0; q < 4; ++q) {
        // U_q = x1 @ W1_q  (B-frag shared between streams)
        f32x4 Uf[2][4];
#pragma unroll
        for (int nt = 0; nt < 4; ++nt) {
            Uf[0][nt] = (f32x4){0.f, 0.f, 0.f, 0.f};
            Uf[1][nt] = Uf[0][nt];
        }
#pragma unroll
        for (int kt = 0; kt < 2; ++kt)
#pragma unroll
            for (int nt = 0; nt < 4; ++nt) {
                f16x8 bf = *(const f16x8*)(fb + W1F_OFF + (q*8 + kt*4 + nt) * 1024 + lane * 16);
                Uf[0][nt] = MFMA16(x1f[0][kt], bf, Uf[0][nt]);
                Uf[1][nt] = MFMA16(x1f[1][kt], bf, Uf[1][nt]);
            }

        // rolled dots per stream; DPP row-sum
        f32x4 xr[2][4];
#pragma unroll
        for (int mt = 0; mt < 2; ++mt) {
            f32x4 p0 = labf[mt][0]*Uf[mt][0] + labf[mt][1]*Uf[mt][1]
                     + labf[mt][2]*Uf[mt][2] + labf[mt][3]*Uf[mt][3];
            f32x4 p1 = labf[mt][0]*Uf[mt][2] + labf[mt][1]*Uf[mt][3]
                     + labf[mt][2]*Uf[mt][0] + labf[mt][3]*Uf[mt][1];
            f32x4 p2 = labf[mt][0]*Uf[mt][3] + labf[mt][1]*Uf[mt][0]
                     + labf[mt][2]*Uf[mt][1] + labf[mt][3]*Uf[mt][2];
#pragma unroll
            for (int j = 0; j < 4; ++j) {
                p0[j] = rowsum16(p0[j]);
                p1[j] = rowsum16(p1[j]);
                p2[j] = rowsum16(p2[j]);
            }
            f32x4 dsel = (pown == 1) ? p1 : (pown == 2) ? p2 : p0;
            f32x4 cand = (dsel + b1xf[mt]) * thlf[mt];
            float* xrb = (mt == 0) ? xrb0 : xrb1;
            *(f32x4*)(xrb + lrow * 16 + kgrp * 4) = cand;
#pragma unroll
            for (int p = 0; p < 4; ++p)
                xr[mt][p] = *(const f32x4*)(xrb + (p * 4 + q) * 16 + kgrp * 4);
        }

        // vq ; stage as f16 A
#pragma unroll
        for (int mt = 0; mt < 2; ++mt) {
            f16* buf = (mt == 0) ? buf0 : buf1;
            f32x4 x03 = xr[mt][0] + xr[mt][3];
#pragma unroll
            for (int nt = 0; nt < 4; ++nt) {
                f32x4 v = labf[mt][nt] * x03
                        + labf[mt][(nt + 2) & 3] * xr[mt][1]
                        + labf[mt][(nt + 1) & 3] * xr[mt][2];
#pragma unroll
                for (int j = 0; j < 4; ++j)
                    buf[(kgrp*4 + j) * 72 + nt*16 + lrow] = (f16)v[j];
            }
        }

        // xo += vq @ W2_q  (B-frag shared)
#pragma unroll
        for (int kt = 0; kt < 2; ++kt) {
            f16x8 av0 = *(const f16x8*)&buf0[lrow * 72 + kt*32 + kgrp*8];
            f16x8 av1 = *(const f16x8*)&buf1[lrow * 72 + kt*32 + kgrp*8];
#pragma unroll
            for (int nt = 0; nt < 4; ++nt) {
                f16x8 bf = *(const f16x8*)(fb + W2F_OFF + (q*8 + kt*4 + nt) * 1024 + lane * 16);
                xof[0][nt] = MFMA16(av0, bf, xof[0][nt]);
                xof[1][nt] = MFMA16(av1, bf, xof[1][nt]);
            }
        }

        // b2 term
#pragma unroll
        for (int p = 0; p < 4; ++p)
#pragma unroll
            for (int nt = 0; nt < 4; ++nt) {
                float bv = b2[(p*4 + q) * 64 + nt*16 + lrow];
                xof[0][nt] += xr[0][p] * bv;
                xof[1][nt] += xr[1][p] * bv;
            }
    }

    // ---------- epilogue: weighted sum over the 16 edges of each node ----------
#pragma unroll
    for (int mt = 0; mt < 2; ++mt) {
        f32x4 ew;
#pragma unroll
        for (int j = 0; j < 4; ++j) {
            float dd = __shfl(dv[mt], kgrp * 4 + j);
            ew[j] = __expf(-dd * 0.1f);
        }
        float cs[4];
#pragma unroll
        for (int nt = 0; nt < 4; ++nt) {
            f32x4 wp = xof[mt][nt] * ew;
            float s = wp[0] + wp[1] + wp[2] + wp[3];
            s += __shfl_xor(s, 16);
            s += __shfl_xor(s, 32);
            cs[nt] = s;
        }
        float v = (kgrp == 0) ? cs[0] : (kgrp == 1) ? cs[1] : (kgrp == 2) ? cs[2] : cs[3];
        out[(size_t)(n0 + mt) * 64 + lane] = v;
    }
}

extern "C" void kernel_launch(void* const* d_in, const int* in_sizes, int n_in,
                              void* d_out, int out_size, void* d_ws, size_t ws_size,
                              hipStream_t stream) {
    const float* h  = (const float*)d_in[0];
    const float* D  = (const float*)d_in[1];
    const float* W0 = (const float*)d_in[2];
    const float* b0 = (const float*)d_in[3];
    const float* W1 = (const float*)d_in[4];
    const float* b1 = (const float*)d_in[5];
    const float* W2 = (const float*)d_in[6];
    const float* b2 = (const float*)d_in[7];
    const float* Wl = (const float*)d_in[8];
    const float* bl = (const float*)d_in[9];
    float* out = (float*)d_out;

    int* selfIdx = (int*)d_ws;            // 4096 ints
    int* nbrIdx  = selfIdx + 4096;        // 65536 ints
    f16* frag    = (f16*)(nbrIdx + 65536);// 77824 bytes

    pre_kernel<<<1043, 256, 0, stream>>>(D, W0, W1, W2, Wl, b1,
                                         selfIdx, nbrIdx, frag);
    node_kernel<<<256, 512, 0, stream>>>(h, b0, b2, bl, frag,
                                         selfIdx, nbrIdx, out);
}